// Round 7
// baseline (188.654 us; speedup 1.0000x reference)
//
#include <hip/hip_runtime.h>
#include <stdint.h>

// Problem constants (fixed by setup_inputs)
#define NROWS 8192
#define DDIM 256
#define NSTRIPS 16
#define STRIP_COLS 512         // NROWS / NSTRIPS
#define GTILES 32              // 16-col tiles per strip
#define BMW 16                 // rows per wave
#define BM 64                  // rows per block (4 waves)
#define NWORK 2048             // NSTRIPS * (NROWS/BM)
#define NMERGE 32              // last-arriving blocks do the merge

// Scores are computed directly in log2-units: e is scaled by sqrt(log2(e)/0.7)
// so acc = s*log2(e) and exp(s) == exp2(acc). Since s <= 1/0.7, exp2(acc) <= 4.17:
// no overflow, so no log-sum-exp shift is needed anywhere.
#define ESCALE 1.4356159f      // sqrt(log2(e)/0.7)
#define LN2F   0.6931471806f
#define NEGBIG (-1e30f)

typedef __attribute__((ext_vector_type(8))) short short8;   // 8 bf16 = 4 VGPRs
typedef __attribute__((ext_vector_type(4))) float f32x4;    // MFMA 16x16 accumulator

__device__ __forceinline__ unsigned short f2bf(float x) {   // RNE float->bf16
  unsigned int u = __float_as_uint(x);
  u += 0x7fffu + ((u >> 16) & 1u);
  return (unsigned short)(u >> 16);
}

// ---------------- Kernel 1: L2-normalize -> scaled bf16 in MFMA-fragment order ----------------
// ebf2 layout: 16B cell (8 bf16 of k) at byte  (idx>>4)*8192 + kc*256 + (idx&15)*16,
// i.e. [group g][k-chunk kc][row-in-group]. Both A and B MFMA fragments load from
// this layout as  base + lane*16  (one contiguous 1 KB dwordx4 per fragment).
__global__ __launch_bounds__(256) void knorm(const float* __restrict__ emb,
                                             unsigned short* __restrict__ ebf2,
                                             float* __restrict__ accv) {
  if (blockIdx.x == 0 && threadIdx.x < 4) accv[threadIdx.x] = 0.f;  // loss,cnt,ctr1,ctr2
  const int wave = threadIdx.x >> 6, lane = threadIdx.x & 63;
  const int row = blockIdx.x * 4 + wave;              // one wave per row
  const float4 v = *(const float4*)(emb + row * DDIM + lane * 4);   // k = lane*4..+3
  float ss = v.x * v.x + v.y * v.y + v.z * v.z + v.w * v.w;
#pragma unroll
  for (int off = 1; off < 64; off <<= 1) ss += __shfl_xor(ss, off, 64);
  const float sc = rsqrtf(ss) * ESCALE;
  ushort4 o;
  o.x = f2bf(v.x * sc); o.y = f2bf(v.y * sc);
  o.z = f2bf(v.z * sc); o.w = f2bf(v.w * sc);
  // fragment-order store: kc = lane>>1, low/high half of the 16B cell = lane&1
  char* dst = (char*)ebf2 + (size_t)(row >> 4) * 8192 + (lane >> 1) * 256 +
              (row & 15) * 16 + (lane & 1) * 8;
  *(ushort4*)dst = o;
}

// ---------------- Kernel 2: barrier-free streaming sims + masks + tail merge ----------------
// grid (NSTRIPS, NROWS/BM) = 2048 blocks; blockIdx.x%8 = XCD so each XCD's L2 only
// sees 2 strips of B (512 KB). No LDS, no __syncthreads in the K-loop: each wave
// holds its 16 A-rows (K=256) in 32 VGPRs and streams B fragments from ebf2 with
// contiguous 1 KB loads; 8 loads in flight x 16 waves/CU hide the L2 latency.
__global__ __launch_bounds__(256, 4) void kmain(const unsigned short* __restrict__ ebf2,
                                                const int* __restrict__ cats,
                                                float* __restrict__ posP,
                                                float* __restrict__ sumP,
                                                float* __restrict__ accv,
                                                float* __restrict__ out) {
  __shared__ int sPrev;
  const int tid = threadIdx.x;
  const int lane = tid & 63, wave = tid >> 6;
  const int lane15 = lane & 15, quad = lane >> 4;
  const int strip = blockIdx.x, rowTile = blockIdx.y;
  const int rowG = rowTile * BM + wave * BMW;         // this wave's 16 rows
  const int ga = rowTile * 4 + wave;                  // A's 16-row group index

  const char* base = (const char*)ebf2;

  // A fragments for the whole kernel: A[m=lane15][k=quad*8+j], 8 x 1KB loads.
  short8 a[8];
  {
    const char* ap = base + (size_t)ga * 8192 + lane * 16;
#pragma unroll
    for (int kk = 0; kk < 8; ++kk) a[kk] = *(const short8*)(ap + kk * 1024);
  }

  // Row categories (C-layout rows = quad*4+r)
  int cati[4];
#pragma unroll
  for (int r = 0; r < 4; ++r) cati[r] = cats[rowG + quad * 4 + r];

  float pm[4] = {NEGBIG, NEGBIG, NEGBIG, NEGBIG};
  float ns[4] = {0.f, 0.f, 0.f, 0.f};

  const int g0 = strip * GTILES;
  const char* bp = base + (size_t)g0 * 8192 + lane * 16;

#pragma unroll 2
  for (int gi = 0; gi < GTILES; ++gi) {
    const int g = g0 + gi;
    const int cj = cats[g * 16 + lane15];             // this tile's 16 col categories
    short8 b[8];
#pragma unroll
    for (int kk = 0; kk < 8; ++kk)
      b[kk] = *(const short8*)(bp + kk * 1024);       // B[k=quad*8+j][n=lane15]
    bp += 8192;

    f32x4 acc = {0.f, 0.f, 0.f, 0.f};
#pragma unroll
    for (int kk = 0; kk < 8; ++kk)
      acc = __builtin_amdgcn_mfma_f32_16x16x32_bf16(a[kk], b[kk], acc, 0, 0, 0);

    const bool dg = (g == ga);                        // wave-uniform: diagonal tile?
#pragma unroll
    for (int r = 0; r < 4; ++r) {
      const float s = acc[r];                         // score in log2-units
      const bool same = (cj == cati[r]);
      float psv = same ? s : NEGBIG;                  // positive candidate
      const float ev = same ? 0.f : __builtin_amdgcn_exp2f(s);  // negative exp
      if (dg && lane15 == quad * 4 + r) psv = NEGBIG; // exclude self on diagonal
      pm[r] = fmaxf(pm[r], psv);
      ns[r] += ev;
    }
  }

  // Reduce across the 16 lanes of each quad (they share rows quad*4+r).
#pragma unroll
  for (int off = 1; off < 16; off <<= 1) {
#pragma unroll
    for (int r = 0; r < 4; ++r) {
      pm[r] = fmaxf(pm[r], __shfl_xor(pm[r], off, 64));
      ns[r] += __shfl_xor(ns[r], off, 64);
    }
  }
  if (lane15 == 0) {
#pragma unroll
    for (int r = 0; r < 4; ++r) {
      const int row = rowG + quad * 4 + r;
      posP[strip * NROWS + row] = pm[r];
      sumP[strip * NROWS + row] = ns[r];
    }
  }

  // ---- tail: last NMERGE arriving blocks merge the 16 slots/row and finalize ----
  __syncthreads();                        // all partial stores issued block-wide
  if (tid == 0) {
    __threadfence();                      // release partials device-wide
    sPrev = atomicAdd((int*)(accv + 2), 1);
  }
  __syncthreads();
  const int prev = sPrev;
  if (prev < NWORK - NMERGE) return;      // early blocks exit
  const int rank = prev - (NWORK - NMERGE);
  if (tid == 0) {
    while (atomicAdd((int*)(accv + 2), 0) < NWORK) __builtin_amdgcn_s_sleep(2);
  }
  __syncthreads();
  __threadfence();                        // acquire: partials now visible

  const int row = rank * 256 + tid;       // NMERGE*256 == NROWS
  float pmv = NEGBIG, nsv = 0.f;
#pragma unroll
  for (int s = 0; s < NSTRIPS; ++s) {
    pmv = fmaxf(pmv, posP[s * NROWS + row]);
    nsv += sumP[s * NROWS + row];
  }
  const bool valid = (pmv > -1e29f) && (nsv > 0.f);
  // pmv is pos*log2(e); loss = ln(exp2(pmv) + sum_neg) - pmv*ln2
  float loss = valid ? (logf(__builtin_amdgcn_exp2f(pmv) + nsv) - pmv * LN2F) : 0.f;
  float cnt = valid ? 1.f : 0.f;
#pragma unroll
  for (int off = 1; off < 64; off <<= 1) {
    loss += __shfl_xor(loss, off, 64);
    cnt += __shfl_xor(cnt, off, 64);
  }
  if (lane == 0) {
    atomicAdd(&accv[0], loss);
    atomicAdd(&accv[1], cnt);
  }
  __syncthreads();
  if (tid == 0) {
    __threadfence();
    const int p2 = atomicAdd((int*)(accv + 3), 1);
    if (p2 == NMERGE - 1) {               // very last block writes the scalar
      const float L = atomicAdd(&accv[0], 0.f);
      const float C = atomicAdd(&accv[1], 0.f);
      out[0] = L / fmaxf(C, 1.f);
    }
  }
}

// ---------------- Launch: 2 dispatches total ----------------
extern "C" void kernel_launch(void* const* d_in, const int* in_sizes, int n_in,
                              void* d_out, int out_size, void* d_ws, size_t ws_size,
                              hipStream_t stream) {
  const float* emb = (const float*)d_in[0];
  const int* cats = (const int*)d_in[1];
  // d_in[2] (font_labels) is unused by the reference.
  float* out = (float*)d_out;

  char* ws = (char*)d_ws;
  float* accv = (float*)ws;                                  // loss, cnt, ctr1, ctr2
  unsigned short* ebf2 = (unsigned short*)(ws + 256);        // 4 MB fragment-order bf16
  float* posP = (float*)(ws + 256 + NROWS * DDIM * 2);       // 16 slots x 8192 (512 KB)
  float* sumP = posP + NSTRIPS * NROWS;                      // 512 KB

  knorm<<<NROWS / 4, 256, 0, stream>>>(emb, ebf2, accv);
  kmain<<<dim3(NSTRIPS, NROWS / BM), 256, 0, stream>>>(ebf2, cats, posP, sumP, accv, out);
}

// Round 8
// 137.822 us; speedup vs baseline: 1.3688x; 1.3688x over previous
//
#include <hip/hip_runtime.h>
#include <stdint.h>

// Problem constants (fixed by setup_inputs)
#define NROWS 8192
#define DDIM 256
#define NSTRIPS 16
#define STRIP_COLS 512         // NROWS / NSTRIPS
#define GTILES 32              // 16-col tiles per strip
#define MT 4                   // 16-row groups per wave (64 rows/wave) — B reuse x4
#define BM 128                 // rows per block (2 waves x 64)
#define NWORK 1024             // NSTRIPS * (NROWS/BM)
#define NMERGE 64              // last-arriving blocks do the merge (128 rows each)

// Scores are computed directly in log2-units: e is scaled by sqrt(log2(e)/0.7)
// so acc = s*log2(e) and exp(s) == exp2(acc). Since s <= 1/0.7, exp2(acc) <= 4.17:
// no overflow, so no log-sum-exp shift is needed anywhere.
#define ESCALE 1.4356159f      // sqrt(log2(e)/0.7)
#define LN2F   0.6931471806f
#define NEGBIG (-1e30f)

typedef __attribute__((ext_vector_type(8))) short short8;   // 8 bf16 = 4 VGPRs
typedef __attribute__((ext_vector_type(4))) float f32x4;    // MFMA 16x16 accumulator

__device__ __forceinline__ unsigned short f2bf(float x) {   // RNE float->bf16
  unsigned int u = __float_as_uint(x);
  u += 0x7fffu + ((u >> 16) & 1u);
  return (unsigned short)(u >> 16);
}

// ---------------- Kernel 1: L2-normalize -> scaled bf16 in MFMA-fragment order ----------------
// ebf2 layout: 16B cell (8 bf16 of k) at byte (row>>4)*8192 + kc*256 + (row&15)*16,
// i.e. [16-row group][k-chunk kc][row-in-group]. Both A and B MFMA fragments load
// from this layout as  base + lane*16  (one contiguous 1 KB dwordx4 per fragment).
__global__ __launch_bounds__(256) void knorm(const float* __restrict__ emb,
                                             unsigned short* __restrict__ ebf2,
                                             float* __restrict__ accv) {
  if (blockIdx.x == 0 && threadIdx.x < 4) accv[threadIdx.x] = 0.f;  // loss,cnt,ctr1,ctr2
  const int wave = threadIdx.x >> 6, lane = threadIdx.x & 63;
  const int row = blockIdx.x * 4 + wave;              // one wave per row
  const float4 v = *(const float4*)(emb + row * DDIM + lane * 4);   // k = lane*4..+3
  float ss = v.x * v.x + v.y * v.y + v.z * v.z + v.w * v.w;
#pragma unroll
  for (int off = 1; off < 64; off <<= 1) ss += __shfl_xor(ss, off, 64);
  const float sc = rsqrtf(ss) * ESCALE;
  ushort4 o;
  o.x = f2bf(v.x * sc); o.y = f2bf(v.y * sc);
  o.z = f2bf(v.z * sc); o.w = f2bf(v.w * sc);
  // fragment-order store: kc = lane>>1, low/high half of the 16B cell = lane&1
  char* dst = (char*)ebf2 + (size_t)(row >> 4) * 8192 + (lane >> 1) * 256 +
              (row & 15) * 16 + (lane & 1) * 8;
  *(ushort4*)dst = o;
}

// ---------------- Kernel 2: barrier-free streaming, 64 rows/wave (B reuse x4) ----------------
// grid (NSTRIPS, NROWS/BM) = 1024 blocks x 128 threads = 2048 waves = 2/SIMD.
// Each wave holds 64 A-rows (a[4][8], 128 VGPRs) and streams its 512-col strip
// ONCE: every 1 KB B fragment feeds 4 MFMAs. K split in halves so the 4 prefetch
// loads hide under 16 dependent MFMAs. No LDS, no K-loop barriers.
__global__ __launch_bounds__(128, 2) void kmain(const unsigned short* __restrict__ ebf2,
                                                const int* __restrict__ cats,
                                                float* __restrict__ posP,
                                                float* __restrict__ sumP,
                                                float* __restrict__ accv,
                                                float* __restrict__ out) {
  __shared__ int sPrev;
  const int tid = threadIdx.x;
  const int lane = tid & 63, wave = tid >> 6;
  const int lane15 = lane & 15, quad = lane >> 4;
  const int strip = blockIdx.x, rowTile = blockIdx.y;
  const int rowG = rowTile * BM + wave * 64;          // this wave's 64 rows
  const int gaBase = rowTile * 8 + wave * 4;          // first of 4 A groups

  const char* base = (const char*)ebf2;

  // A fragments for the whole kernel: a[m] covers rows gaBase+m, A[lane15][k=quad*8+j]
  short8 a[MT][8];
#pragma unroll
  for (int m = 0; m < MT; ++m) {
    const char* ap = base + (size_t)(gaBase + m) * 8192 + lane * 16;
#pragma unroll
    for (int kk = 0; kk < 8; ++kk) a[m][kk] = *(const short8*)(ap + kk * 1024);
  }

  // Row categories (C-layout rows = m*16 + quad*4 + r)
  int cati[MT][4];
#pragma unroll
  for (int m = 0; m < MT; ++m)
#pragma unroll
    for (int r = 0; r < 4; ++r) cati[m][r] = cats[rowG + m * 16 + quad * 4 + r];

  float pm[MT][4], ns[MT][4];
#pragma unroll
  for (int m = 0; m < MT; ++m)
#pragma unroll
    for (int r = 0; r < 4; ++r) { pm[m][r] = NEGBIG; ns[m][r] = 0.f; }

  const int g0 = strip * GTILES;
  const char* bp = base + (size_t)g0 * 8192 + lane * 16;

  short8 bb[2][4];                                    // K-half ping-pong (32 VGPRs)
#pragma unroll
  for (int kk = 0; kk < 4; ++kk) bb[0][kk] = *(const short8*)(bp + kk * 1024);

  for (int gi = 0; gi < GTILES; ++gi) {
    const int g = g0 + gi;
    const int cj = cats[g * 16 + lane15];             // this tile's 16 col categories

    // prefetch K-half 1, compute half 0
#pragma unroll
    for (int kk = 0; kk < 4; ++kk) bb[1][kk] = *(const short8*)(bp + (4 + kk) * 1024);
    f32x4 acc[MT];
#pragma unroll
    for (int m = 0; m < MT; ++m) {
      acc[m] = (f32x4){0.f, 0.f, 0.f, 0.f};
#pragma unroll
      for (int kk = 0; kk < 4; ++kk)
        acc[m] = __builtin_amdgcn_mfma_f32_16x16x32_bf16(a[m][kk], bb[0][kk], acc[m], 0, 0, 0);
    }
    // prefetch next tile's K-half 0, compute half 1
    bp += 8192;
    if (gi + 1 < GTILES) {
#pragma unroll
      for (int kk = 0; kk < 4; ++kk) bb[0][kk] = *(const short8*)(bp + kk * 1024);
    }
#pragma unroll
    for (int m = 0; m < MT; ++m)
#pragma unroll
      for (int kk = 0; kk < 4; ++kk)
        acc[m] = __builtin_amdgcn_mfma_f32_16x16x32_bf16(a[m][4 + kk], bb[1][kk], acc[m], 0, 0, 0);

    // epilogue: 16 scores/lane
#pragma unroll
    for (int m = 0; m < MT; ++m) {
      const bool dg = (g == gaBase + m);              // wave-uniform: diagonal tile?
#pragma unroll
      for (int r = 0; r < 4; ++r) {
        const float s = acc[m][r];                    // score in log2-units
        const bool same = (cj == cati[m][r]);
        float psv = same ? s : NEGBIG;                // positive candidate
        const float ev = same ? 0.f : __builtin_amdgcn_exp2f(s);  // negative exp
        if (dg && lane15 == quad * 4 + r) psv = NEGBIG;  // exclude self on diagonal
        pm[m][r] = fmaxf(pm[m][r], psv);
        ns[m][r] += ev;
      }
    }
  }

  // Reduce across the 16 lanes of each quad (they share rows m*16+quad*4+r).
#pragma unroll
  for (int off = 1; off < 16; off <<= 1) {
#pragma unroll
    for (int m = 0; m < MT; ++m)
#pragma unroll
      for (int r = 0; r < 4; ++r) {
        pm[m][r] = fmaxf(pm[m][r], __shfl_xor(pm[m][r], off, 64));
        ns[m][r] += __shfl_xor(ns[m][r], off, 64);
      }
  }
  if (lane15 == 0) {
#pragma unroll
    for (int m = 0; m < MT; ++m)
#pragma unroll
      for (int r = 0; r < 4; ++r) {
        const int row = rowG + m * 16 + quad * 4 + r;
        posP[strip * NROWS + row] = pm[m][r];
        sumP[strip * NROWS + row] = ns[m][r];
      }
  }

  // ---- tail: last NMERGE arriving blocks merge the 16 slots/row and finalize ----
  __syncthreads();                        // all partial stores issued block-wide
  if (tid == 0) {
    __threadfence();                      // release partials device-wide
    sPrev = atomicAdd((int*)(accv + 2), 1);
  }
  __syncthreads();
  const int prev = sPrev;
  if (prev < NWORK - NMERGE) return;      // early blocks exit
  const int rank = prev - (NWORK - NMERGE);
  if (tid == 0) {
    while (atomicAdd((int*)(accv + 2), 0) < NWORK) __builtin_amdgcn_s_sleep(2);
  }
  __syncthreads();
  __threadfence();                        // acquire: partials now visible

  const int row = rank * 128 + tid;       // NMERGE*128 == NROWS
  float pmv = NEGBIG, nsv = 0.f;
#pragma unroll
  for (int s = 0; s < NSTRIPS; ++s) {
    pmv = fmaxf(pmv, posP[s * NROWS + row]);
    nsv += sumP[s * NROWS + row];
  }
  const bool valid = (pmv > -1e29f) && (nsv > 0.f);
  // pmv is pos*log2(e); loss = ln(exp2(pmv) + sum_neg) - pmv*ln2
  float loss = valid ? (logf(__builtin_amdgcn_exp2f(pmv) + nsv) - pmv * LN2F) : 0.f;
  float cnt = valid ? 1.f : 0.f;
#pragma unroll
  for (int off = 1; off < 64; off <<= 1) {
    loss += __shfl_xor(loss, off, 64);
    cnt += __shfl_xor(cnt, off, 64);
  }
  if (lane == 0) {
    atomicAdd(&accv[0], loss);
    atomicAdd(&accv[1], cnt);
  }
  __syncthreads();
  if (tid == 0) {
    __threadfence();
    const int p2 = atomicAdd((int*)(accv + 3), 1);
    if (p2 == NMERGE - 1) {               // very last block writes the scalar
      const float L = atomicAdd(&accv[0], 0.f);
      const float C = atomicAdd(&accv[1], 0.f);
      out[0] = L / fmaxf(C, 1.f);
    }
  }
}

// ---------------- Launch: 2 dispatches total ----------------
extern "C" void kernel_launch(void* const* d_in, const int* in_sizes, int n_in,
                              void* d_out, int out_size, void* d_ws, size_t ws_size,
                              hipStream_t stream) {
  const float* emb = (const float*)d_in[0];
  const int* cats = (const int*)d_in[1];
  // d_in[2] (font_labels) is unused by the reference.
  float* out = (float*)d_out;

  char* ws = (char*)d_ws;
  float* accv = (float*)ws;                                  // loss, cnt, ctr1, ctr2
  unsigned short* ebf2 = (unsigned short*)(ws + 256);        // 4 MB fragment-order bf16
  float* posP = (float*)(ws + 256 + NROWS * DDIM * 2);       // 16 slots x 8192 (512 KB)
  float* sumP = posP + NSTRIPS * NROWS;                      // 512 KB

  knorm<<<NROWS / 4, 256, 0, stream>>>(emb, ebf2, accv);
  kmain<<<dim3(NSTRIPS, NROWS / BM), 128, 0, stream>>>(ebf2, cats, posP, sumP, accv, out);
}